// Round 11
// baseline (144.491 us; speedup 1.0000x reference)
//
#include <hip/hip_runtime.h>

// CRF loss: sum_b(forward_score[b] - gold_score[b]).  B=512, T=1024, L=32.
//
// R16b = R16 pair-product restructuring, LOOP BOUNDS FIXED.
// R16 crashed (core dump = device fault): main loop ran s0 < 2*CL-8 (256
// timesteps/wave, 2x the chunk) -> refill read emB out to t0+255 -> OOB for
// w=7/b=511. Fix: s0 < CL-8, tail at CL-8..CL-2 (64 pairs = 128 timesteps).
//
// Theory (unchanged, untested until now): wall = per-wave serial chain
// {M-pack -> MFMA1 -> chained MFMA2}, ~300cy x 128 links; waves only fill
// issue slots under it (R15b skew null, R13b half-occupancy -10%, R14 VALU-
// on-path +13%). Re-associate: Phi_p = A_{2p+1}*A_{2p} OFF-chain (pure ILP),
// chain does M <- Phi*M: 64 links. MFMA count unchanged.
// Layout: compute Phi^T = A1^T * A2^T.
//  - B-op = A2^T[k,c] = f2[c]*E[c,k]: lane-own f2 x own E-row = the proven
//    A-frag build (fs2*E0v/E1v, reused verbatim).
//  - A-op = A1^T[r,k] = f1[k]*E[k,r]: E-cols (preamble) x f1 broadcast via
//    32-float LDS buffer (lane writes own exp; f32x4 reads at slots
//    kappa(h,e) = (e&3)+8(e>>2)+4h; double-buffered one pair ahead).
//  - Phi^T C/D (lane j = row j of Phi, cols rho(reg,h)=(reg&3)+8(reg>>2)+4h)
//    aligns exactly with the chain A-frag slot map -> PF-pack = proven
//    B-pack pattern (16 reads + 8 perms). M init = I (identity B-frags);
//    link 0 = Phi_0 * I.
// Renorm: measure at odd pairs (every 4 timesteps, proxy exp of acc[2]
// lane 0, exact 2^-e), apply into next even pair's f2; last e un-applied.
// launch_bounds(512,3): ~170-reg cap, no spill at the larger live set
// (1 blk/CU; R13b priced that at ~10%; chain halving should dominate).
// Gold preamble + wave-0 combine unchanged (proven exact).

typedef float  f32x16 __attribute__((ext_vector_type(16)));
typedef short  s16x8  __attribute__((ext_vector_type(8)));
typedef float  f32x2  __attribute__((ext_vector_type(2)));
typedef float  f32x4  __attribute__((ext_vector_type(4)));

#define TT 1024
#define LL 32
#define BB 512
#define NC 8
#define CL 128
#define MS 33

union Frag { s16x8 v; unsigned u[4]; };

// pack two f32 -> u32 holding 2 bf16 (truncation): lo in [15:0], hi in [31:16]
__device__ __forceinline__ unsigned pack_bf16(float lo, float hi) {
    return __builtin_amdgcn_perm(__float_as_uint(hi), __float_as_uint(lo), 0x07060302u);
}

__global__ __launch_bounds__(NC * 64, 3) void crf_fused_kernel(
    const float* __restrict__ emission,    // [B, T, L]
    const int*   __restrict__ label_ids,   // [B, T]
    const float* __restrict__ transitions, // [L, L]
    float*       __restrict__ out)         // [1], pre-zeroed
{
    __shared__ __align__(16) float shM[NC][32 * MS];   // 33,792 B
    __shared__ __align__(16) float shF[NC][2][32];     // f1 broadcast, dbuf
    __shared__ float shQ[2][64];
    __shared__ float tgArr[NC];
    __shared__ int   capArr[NC];

    const int tid  = threadIdx.x;
    const int w    = tid >> 6;             // wave id = chunk id
    const int lane = tid & 63;
    const int j    = lane & 31;            // A row / C-D col
    const int h    = lane >> 5;            // k-half
    const int b    = blockIdx.x;
    const int t0   = w * CL;

    const int*   labB = label_ids + b * TT + t0;
    const float* emB  = emission + ((size_t)b * TT + t0) * LL + j;

    // ---- gold score partial (transitions + emission gather), preamble ----
    {
        float g = 0.0f;
#pragma unroll
        for (int u = 0; u < 2; ++u) {
            int tt = t0 + 64 * u + lane;
            int l1 = labB[64 * u + lane];
            int l0 = (tt == 0) ? 0 : label_ids[b * TT + tt - 1];   // SOS at -1
            g += transitions[(l1 << 5) + l0];
            g += emission[((size_t)b * TT + tt) * LL + l1];
            if (tt == TT - 1) g += transitions[32 + l1];           // trans[END,last]
        }
#pragma unroll
        for (int m = 32; m >= 1; m >>= 1) g += __shfl_xor(g, m, 64);
        if (lane == 0) tgArr[w] = g;
    }

    // ---- E rows (sigma cols): B-op of the pair product (= proven A-frag) ----
    const float* trow = transitions + j * 32;
    f32x2 E0v[4], E1v[4];
    // ---- E cols (sigma rows): A-op of the pair product ----
    f32x2 EcA[4], EcB[4];
#pragma unroll
    for (int p = 0; p < 4; ++p) {
        int c0 = ((2 * p) & 3)     + 8 * ((2 * p) >> 2)     + 4 * h;
        int c1 = ((2 * p + 1) & 3) + 8 * ((2 * p + 1) >> 2) + 4 * h;
        E0v[p][0] = __expf(trow[c0]);      E0v[p][1] = __expf(trow[c1]);
        E1v[p][0] = __expf(trow[16 + c0]); E1v[p][1] = __expf(trow[16 + c1]);
        EcA[p][0] = __expf(transitions[c0 * 32 + j]);
        EcA[p][1] = __expf(transitions[c1 * 32 + j]);
        EcB[p][0] = __expf(transitions[(c0 + 16) * 32 + j]);
        EcB[p][1] = __expf(transitions[(c1 + 16) * 32 + j]);
    }

    // ---- Bf = identity in sigma layout (M init; bf16 1.0 = 0x3F80) ----
    Frag Bf0, Bf1;
#pragma unroll
    for (int i = 0; i < 8; ++i) {
        int row = (i & 3) + 8 * (i >> 2) + 4 * h;
        Bf0.v[i] = (short)((row == j)      ? 0x3F80 : 0);
        Bf1.v[i] = (short)((row + 16 == j) ? 0x3F80 : 0);
    }

    f32x16 zc, acc;
#pragma unroll
    for (int i = 0; i < 16; ++i) zc[i] = 0.0f;

    float ring[8];
#pragma unroll
    for (int s = 0; s < 8; ++s) ring[s] = emB[s * LL];

    // f1 for pair 0 (timestep 0) into LDS buffer 0
    shF[w][0][j] = __expf(ring[0]);

    float sc = 1.0f;
    int   Cap = 0, elast = 0;

    // one pair (timesteps s, s+1); pk = (s/2)&1 (= LDS buf and renorm phase)
    auto pairstep = [&](int k1, int k2, int s, bool refill, int pk) {
        // B-op frags: A2^T = f2 * own E-row (identical to proven A-frag build)
        float f2 = __expf(ring[k2]);
        if (pk == 0) f2 *= sc;             // apply pending renorm scale
        f32x2 f2v; f2v[0] = f2; f2v[1] = f2;
        Frag V20, V21;
#pragma unroll
        for (int q = 0; q < 4; ++q) {
            f32x2 a = f2v * E0v[q];
            f32x2 c = f2v * E1v[q];
            V20.u[q] = pack_bf16(a[0], a[1]);
            V21.u[q] = pack_bf16(c[0], c[1]);
        }

        // A-op frags: A1^T = f1[k] (LDS broadcast) * E-col
        const f32x4* fp = (const f32x4*)(&shF[w][pk][0]);
        f32x4 fA = fp[h], fB = fp[2 + h], fC = fp[4 + h], fD = fp[6 + h];
        Frag T0, T1;
        {
            f32x2 u;
            u[0] = fA[0]; u[1] = fA[1]; u *= EcA[0]; T0.u[0] = pack_bf16(u[0], u[1]);
            u[0] = fA[2]; u[1] = fA[3]; u *= EcA[1]; T0.u[1] = pack_bf16(u[0], u[1]);
            u[0] = fB[0]; u[1] = fB[1]; u *= EcA[2]; T0.u[2] = pack_bf16(u[0], u[1]);
            u[0] = fB[2]; u[1] = fB[3]; u *= EcA[3]; T0.u[3] = pack_bf16(u[0], u[1]);
            u[0] = fC[0]; u[1] = fC[1]; u *= EcB[0]; T1.u[0] = pack_bf16(u[0], u[1]);
            u[0] = fC[2]; u[1] = fC[3]; u *= EcB[1]; T1.u[1] = pack_bf16(u[0], u[1]);
            u[0] = fD[0]; u[1] = fD[1]; u *= EcB[2]; T1.u[2] = pack_bf16(u[0], u[1]);
            u[0] = fD[2]; u[1] = fD[3]; u *= EcB[3]; T1.u[3] = pack_bf16(u[0], u[1]);
        }

        // pair product Phi^T = A1^T * A2^T  (OFF the M-chain; pure ILP)
        f32x16 pacc = __builtin_amdgcn_mfma_f32_32x32x16_bf16(T0.v, V20.v, zc, 0, 0, 0);
        pacc = __builtin_amdgcn_mfma_f32_32x32x16_bf16(T1.v, V21.v, pacc, 0, 0, 0);

        // publish f1 for the NEXT pair (timestep s+2; slot holds it already)
        shF[w][pk ^ 1][j] = __expf(ring[(k1 + 2) & 7]);

        if (refill) {
            ring[k1] = emB[(s + 8) * LL];
            ring[k2] = emB[(s + 9) * LL];
        }

        // Phi-pack: Phi^T C/D rows rho(reg,h) == chain-A slot map kappa(h,e)
        Frag PF0, PF1;
#pragma unroll
        for (int q = 0; q < 4; ++q) {
            PF0.u[q] = pack_bf16(pacc[2 * q],     pacc[2 * q + 1]);
            PF1.u[q] = pack_bf16(pacc[8 + 2 * q], pacc[9 + 2 * q]);
        }

        // chain link: M <- Phi * M   (the only serial part; 64 links total)
        acc = __builtin_amdgcn_mfma_f32_32x32x16_bf16(PF0.v, Bf0.v, zc, 0, 0, 0);
        acc = __builtin_amdgcn_mfma_f32_32x32x16_bf16(PF1.v, Bf1.v, acc, 0, 0, 0);

        if (pk) {                          // odd pair = 4 timesteps: renorm
            int pb = __builtin_amdgcn_readlane(__float_as_int(acc[2]), 0);
            int e  = ((pb >> 23) & 0xff) - 127;
            sc = __int_as_float((127 - e) << 23);   // exact 2^-e
            Cap += e;
            elast = e;
        }

        // M-pack for the next link (sigma layout, direct reg feed)
#pragma unroll
        for (int q = 0; q < 4; ++q) {
            Bf0.u[q] = pack_bf16(acc[2 * q],     acc[2 * q + 1]);
            Bf1.u[q] = pack_bf16(acc[8 + 2 * q], acc[9 + 2 * q]);
        }
    };

    // 60 pairs with refill (timesteps 0..119), 4 tail pairs (120..127).
    for (int s0 = 0; s0 < CL - 8; s0 += 8) {
        pairstep(0, 1, s0 + 0, true, 0);
        pairstep(2, 3, s0 + 2, true, 1);
        pairstep(4, 5, s0 + 4, true, 0);
        pairstep(6, 7, s0 + 6, true, 1);
    }
    pairstep(0, 1, CL - 8, false, 0);      // tail: no refill
    pairstep(2, 3, CL - 6, false, 1);
    pairstep(4, 5, CL - 4, false, 0);
    pairstep(6, 7, CL - 2, false, 1);

    Cap -= elast;                          // final measured e never applied

    // ---- store M_c to LDS (f32, padded stride -> conflict-free) ----
#pragma unroll
    for (int r = 0; r < 16; ++r) {
        int row = (r & 3) + 8 * (r >> 2) + 4 * h;
        shM[w][row * MS + j] = acc[r];
    }
    if (lane == 0) capArr[w] = Cap;

    __syncthreads();

    // ---- wave 0: sequential 8-chunk matvec combine ----
    if (w == 0) {
        const float Eend = __expf(transitions[32 + j]);   // exp(trans[END][j])
        float q = (j == 0) ? 1.0f : 0.0f;                 // one-hot SOS
        int   Cq = 0;
        float gold = 0.0f;

#pragma unroll
        for (int c = 0; c < NC; ++c) {
            shQ[c & 1][lane] = q;
            asm volatile("s_waitcnt lgkmcnt(0)" ::: "memory");
            __builtin_amdgcn_wave_barrier();
            const float* Mrow = &shM[c][j * MS];
            const float* qv   = &shQ[c & 1][h * 32];
            float a0 = 0.f, a1 = 0.f, a2 = 0.f, a3 = 0.f;
#pragma unroll
            for (int i = 0; i < 32; i += 4) {
                a0 = fmaf(Mrow[i],     qv[i],     a0);
                a1 = fmaf(Mrow[i + 1], qv[i + 1], a1);
                a2 = fmaf(Mrow[i + 2], qv[i + 2], a2);
                a3 = fmaf(Mrow[i + 3], qv[i + 3], a3);
            }
            float qn = (a0 + a1) + (a2 + a3);
            int pb = __builtin_amdgcn_readlane(__float_as_int(qn), 2);
            int e  = ((pb >> 23) & 0xff) - 127;
            qn *= __int_as_float((127 - e) << 23);        // exact 2^-e
            Cq += e + capArr[c];
            gold += tgArr[c];
            q = qn;
        }

        float v = q * Eend;
#pragma unroll
        for (int m = 16; m >= 1; m >>= 1) v += __shfl_xor(v, m, 32);
        float fwd = __logf(v) + (float)Cq * 0.69314718055994531f;

        if (lane == 0) atomicAdd(out, fwd - gold);
    }
}

extern "C" void kernel_launch(void* const* d_in, const int* in_sizes, int n_in,
                              void* d_out, int out_size, void* d_ws, size_t ws_size,
                              hipStream_t stream)
{
    const float* emission    = (const float*)d_in[0];
    const int*   label_ids   = (const int*)d_in[1];
    const float* transitions = (const float*)d_in[2];
    float* out = (float*)d_out;

    (void)hipMemsetAsync(out, 0, sizeof(float), stream);
    crf_fused_kernel<<<BB, NC * 64, 0, stream>>>(emission, label_ids, transitions, out);
}

// Round 12
// 134.667 us; speedup vs baseline: 1.0730x; 1.0730x over previous
//
#include <hip/hip_runtime.h>

// CRF loss: sum_b(forward_score[b] - gold_score[b]).  B=512, T=1024, L=32.
//
// R17 = constant-A factorization: M <- D_f (*) (E*M).
// Decisive R16b datum: chain halved (64 links), MFMA count same, VALU/step
// same -> time SAME (71 vs 65). With R14 (+VALU -> +time), R15b (skew null),
// R13b (half waves -> -10%): wall tracks VALU instructions per timestep,
// nothing else. So: cut VALU/step.
// The A-frag build (8 pk_mul + 8 perm/step) exists only because A_t = f_t(*)E
// bakes the diagonal in. Re-factor: E is a CONSTANT pre-packed A-frag
// (preamble); the diagonal f_t applies during the B-repack that already
// exists: M_t[row,col] = f_t[row]*(E*M)[row,col]. f per-ROW delivered by the
// R16b-proven LDS broadcast: lane publishes exp(ring) one step ahead into
// shF[2][32]; reads 4x ds_read_b128 at rho-slots {0,8,16,24}+4h (fp[h],
// fp[2+h],fp[4+h],fp[6+h] pair exactly with acc[2p],acc[2p+1] rows).
// Renorm: measured from unscaled acc[2] (same proxy, exact 2^-e); sc folded
// into the published f when (s+1)%4==0 (measured same step s%4==3); last e
// un-applied (Cap -= elast) - semantics identical to R8b.
// Final store uses the scaled values (M includes f).
// Net/step: -8 pk_mul -8 perm (A-build gone), +8 pk_mul (scale, fused into
// repack), +1 ds_write +4 ds_read (lgkm pipe, prefetched 1 step ahead).
// VALU ~65 -> ~50/step; serial path = acc -> scale-pack -> MFMA -> acc.
// Predict 48-56us. Everything else R8b verbatim (proven exact): 8 waves x
// 128 steps, ring-8 refill with tail split, gold preamble, wave-0 combine.

typedef float  f32x16 __attribute__((ext_vector_type(16)));
typedef short  s16x8  __attribute__((ext_vector_type(8)));
typedef float  f32x2  __attribute__((ext_vector_type(2)));
typedef float  f32x4  __attribute__((ext_vector_type(4)));

#define TT 1024
#define LL 32
#define BB 512
#define NC 8
#define CL 128
#define MS 33

union Frag { s16x8 v; unsigned u[4]; };

// pack two f32 -> u32 holding 2 bf16 (truncation): lo in [15:0], hi in [31:16]
__device__ __forceinline__ unsigned pack_bf16(float lo, float hi) {
    return __builtin_amdgcn_perm(__float_as_uint(hi), __float_as_uint(lo), 0x07060302u);
}

__global__ __launch_bounds__(NC * 64, 4) void crf_fused_kernel(
    const float* __restrict__ emission,    // [B, T, L]
    const int*   __restrict__ label_ids,   // [B, T]
    const float* __restrict__ transitions, // [L, L]
    float*       __restrict__ out)         // [1], pre-zeroed
{
    __shared__ __align__(16) float shM[NC][32 * MS];   // 33,792 B
    __shared__ __align__(16) float shF[NC][2][32];     // f broadcast, dbuf
    __shared__ float shQ[2][64];
    __shared__ float tgArr[NC];
    __shared__ int   capArr[NC];

    const int tid  = threadIdx.x;
    const int w    = tid >> 6;             // wave id = chunk id
    const int lane = tid & 63;
    const int j    = lane & 31;            // A row / C-D col
    const int h    = lane >> 5;            // k-half
    const int b    = blockIdx.x;
    const int t0   = w * CL;

    const int*   labB = label_ids + b * TT + t0;
    const float* emB  = emission + ((size_t)b * TT + t0) * LL + j;

    // ---- gold score partial (transitions + emission gather), preamble ----
    {
        float g = 0.0f;
#pragma unroll
        for (int u = 0; u < 2; ++u) {
            int tt = t0 + 64 * u + lane;
            int l1 = labB[64 * u + lane];
            int l0 = (tt == 0) ? 0 : label_ids[b * TT + tt - 1];   // SOS at -1
            g += transitions[(l1 << 5) + l0];
            g += emission[((size_t)b * TT + tt) * LL + l1];
            if (tt == TT - 1) g += transitions[32 + l1];           // trans[END,last]
        }
#pragma unroll
        for (int m = 32; m >= 1; m >>= 1) g += __shfl_xor(g, m, 64);
        if (lane == 0) tgArr[w] = g;
    }

    // ---- E as CONSTANT A-frags, sigma k-order (built once) ----
    const float* trow = transitions + j * 32;
    Frag Ea0, Ea1;
#pragma unroll
    for (int p = 0; p < 4; ++p) {
        int c0 = ((2 * p) & 3)     + 8 * ((2 * p) >> 2)     + 4 * h;
        int c1 = ((2 * p + 1) & 3) + 8 * ((2 * p + 1) >> 2) + 4 * h;
        Ea0.u[p] = pack_bf16(__expf(trow[c0]),      __expf(trow[c1]));
        Ea1.u[p] = pack_bf16(__expf(trow[16 + c0]), __expf(trow[16 + c1]));
    }

    // ---- B = identity in sigma layout (M init; bf16 1.0 = 0x3F80) ----
    Frag B0, B1;
#pragma unroll
    for (int i = 0; i < 8; ++i) {
        int row = (i & 3) + 8 * (i >> 2) + 4 * h;
        B0.v[i] = (short)((row == j)      ? 0x3F80 : 0);
        B1.v[i] = (short)((row + 16 == j) ? 0x3F80 : 0);
    }

    f32x16 zc, acc;
#pragma unroll
    for (int i = 0; i < 16; ++i) zc[i] = 0.0f;

    float ring[8];
#pragma unroll
    for (int s = 0; s < 8; ++s) ring[s] = emB[s * LL];

    // publish f_0 into buffer 0
    shF[w][0][j] = __expf(ring[0]);

    float sc = 1.0f;
    int   Cap = 0, elast = 0;
    f32x2 sm0[4], sm1[4];                  // scaled M (persists for store)

    // one recurrence step; refill only when told (tail has none)
    auto step = [&](int k, int s, bool refill) {
        // f_s broadcast (published one step ago) at rho-slot offsets
        const f32x4* fp = (const f32x4*)(&shF[w][s & 1][0]);
        f32x4 fA = fp[h], fB = fp[2 + h], fC = fp[4 + h], fD = fp[6 + h];

        // E*M with constant A-frags
        acc = __builtin_amdgcn_mfma_f32_32x32x16_bf16(Ea0.v, B0.v, zc, 0, 0, 0);
        acc = __builtin_amdgcn_mfma_f32_32x32x16_bf16(Ea1.v, B1.v, acc, 0, 0, 0);

        if ((s & 3) == 3) {                // renorm measure (unscaled proxy)
            int pb = __builtin_amdgcn_readlane(__float_as_int(acc[2]), 0);
            int e  = ((pb >> 23) & 0xff) - 127;
            sc = __int_as_float((127 - e) << 23);   // exact 2^-e
            Cap += e;
            elast = e;
        }

        // publish f_{s+1} (ring slot (k+1)&7 holds timestep s+1);
        // fold sc in when the next step is a renorm-apply step.
        {
            float fn = __expf(ring[(k + 1) & 7]);
            if (((s + 1) & 3) == 0) fn *= sc;
            shF[w][(s + 1) & 1][j] = fn;
        }

        if (refill) ring[k] = emB[(s + 8) * LL];

        // scale + pack: M_s = f_s (*) acc   (rows rho(r,h) <- fA/fB/fC/fD)
        f32x2 fv, av;
        fv[0] = fA[0]; fv[1] = fA[1]; av[0] = acc[0];  av[1] = acc[1];  sm0[0] = fv * av;
        fv[0] = fA[2]; fv[1] = fA[3]; av[0] = acc[2];  av[1] = acc[3];  sm0[1] = fv * av;
        fv[0] = fB[0]; fv[1] = fB[1]; av[0] = acc[4];  av[1] = acc[5];  sm0[2] = fv * av;
        fv[0] = fB[2]; fv[1] = fB[3]; av[0] = acc[6];  av[1] = acc[7];  sm0[3] = fv * av;
        fv[0] = fC[0]; fv[1] = fC[1]; av[0] = acc[8];  av[1] = acc[9];  sm1[0] = fv * av;
        fv[0] = fC[2]; fv[1] = fC[3]; av[0] = acc[10]; av[1] = acc[11]; sm1[1] = fv * av;
        fv[0] = fD[0]; fv[1] = fD[1]; av[0] = acc[12]; av[1] = acc[13]; sm1[2] = fv * av;
        fv[0] = fD[2]; fv[1] = fD[3]; av[0] = acc[14]; av[1] = acc[15]; sm1[3] = fv * av;

#pragma unroll
        for (int q = 0; q < 4; ++q) {
            B0.u[q] = pack_bf16(sm0[q][0], sm0[q][1]);
            B1.u[q] = pack_bf16(sm1[q][0], sm1[q][1]);
        }
    };

    for (int s0 = 0; s0 < CL - 8; s0 += 8) {
#pragma unroll
        for (int k = 0; k < 8; ++k) step(k, s0 + k, true);
    }
#pragma unroll
    for (int k = 0; k < 8; ++k) step(k, CL - 8 + k, false);

    Cap -= elast;                          // final measured e never applied

    // ---- store M_c (scaled values) to LDS (padded stride) ----
#pragma unroll
    for (int r = 0; r < 16; ++r) {
        int row = (r & 3) + 8 * (r >> 2) + 4 * h;
        float val = (r < 8) ? sm0[r >> 1][r & 1] : sm1[(r >> 1) - 4][r & 1];
        shM[w][row * MS + j] = val;
    }
    if (lane == 0) capArr[w] = Cap;

    __syncthreads();

    // ---- wave 0: sequential 8-chunk matvec combine ----
    if (w == 0) {
        const float Eend = __expf(transitions[32 + j]);   // exp(trans[END][j])
        float q = (j == 0) ? 1.0f : 0.0f;                 // one-hot SOS
        int   Cq = 0;
        float gold = 0.0f;

#pragma unroll
        for (int c = 0; c < NC; ++c) {
            shQ[c & 1][lane] = q;
            asm volatile("s_waitcnt lgkmcnt(0)" ::: "memory");
            __builtin_amdgcn_wave_barrier();
            const float* Mrow = &shM[c][j * MS];
            const float* qv   = &shQ[c & 1][h * 32];
            float a0 = 0.f, a1 = 0.f, a2 = 0.f, a3 = 0.f;
#pragma unroll
            for (int i = 0; i < 32; i += 4) {
                a0 = fmaf(Mrow[i],     qv[i],     a0);
                a1 = fmaf(Mrow[i + 1], qv[i + 1], a1);
                a2 = fmaf(Mrow[i + 2], qv[i + 2], a2);
                a3 = fmaf(Mrow[i + 3], qv[i + 3], a3);
            }
            float qn = (a0 + a1) + (a2 + a3);
            int pb = __builtin_amdgcn_readlane(__float_as_int(qn), 2);
            int e  = ((pb >> 23) & 0xff) - 127;
            qn *= __int_as_float((127 - e) << 23);        // exact 2^-e
            Cq += e + capArr[c];
            gold += tgArr[c];
            q = qn;
        }

        float v = q * Eend;
#pragma unroll
        for (int m = 16; m >= 1; m >>= 1) v += __shfl_xor(v, m, 32);
        float fwd = __logf(v) + (float)Cq * 0.69314718055994531f;

        if (lane == 0) atomicAdd(out, fwd - gold);
    }
}

extern "C" void kernel_launch(void* const* d_in, const int* in_sizes, int n_in,
                              void* d_out, int out_size, void* d_ws, size_t ws_size,
                              hipStream_t stream)
{
    const float* emission    = (const float*)d_in[0];
    const int*   label_ids   = (const int*)d_in[1];
    const float* transitions = (const float*)d_in[2];
    float* out = (float*)d_out;

    (void)hipMemsetAsync(out, 0, sizeof(float), stream);
    crf_fused_kernel<<<BB, NC * 64, 0, stream>>>(emission, label_ids, transitions, out);
}